// Round 4
// baseline (142.306 us; speedup 1.0000x reference)
//
#include <hip/hip_runtime.h>
#include <math.h>

#define EPS 1e-6f

typedef _Float16 half8 __attribute__((ext_vector_type(8)));
typedef float f32x16 __attribute__((ext_vector_type(16)));

// ---------------- Kernel 1: h = LayerNorm(relu(x @ Wh + bh)) ----------------
// 64 blocks x 512 threads; thread t owns column t
__global__ __launch_bounds__(512) void k_fch_ln(
    const float* __restrict__ x, const float* __restrict__ Wh,
    const float* __restrict__ bh, const float* __restrict__ ls,
    const float* __restrict__ lb, float* __restrict__ hout) {
    const int b = blockIdx.x;
    const int t = threadIdx.x;
    __shared__ float xs[512];
    __shared__ float wred[2][8];

    xs[t] = x[b * 512 + t];
    __syncthreads();

    float acc = bh[t];
#pragma unroll 8
    for (int k = 0; k < 512; ++k)
        acc = fmaf(xs[k], Wh[k * 512 + t], acc);
    acc = fmaxf(acc, 0.0f);

    float s = acc, ss = acc * acc;
#pragma unroll
    for (int m = 1; m < 64; m <<= 1) {
        s  += __shfl_xor(s, m);
        ss += __shfl_xor(ss, m);
    }
    const int wv = t >> 6;
    if ((t & 63) == 0) { wred[0][wv] = s; wred[1][wv] = ss; }
    __syncthreads();
    s = 0.f; ss = 0.f;
#pragma unroll
    for (int i = 0; i < 8; ++i) { s += wred[0][i]; ss += wred[1][i]; }

    float mean = s * (1.0f / 512.0f);
    float var  = ss * (1.0f / 512.0f) - mean * mean;
    float rstd = rsqrtf(var + EPS);
    hout[b * 512 + t] = (acc - mean) * rstd * ls[t] + lb[t];
}

// ---------------- Kernel 2: xz{1,2} = x @ Wz{1,2}[:512,:] ------------------
// grid (8, 32, 2): 8-row group, (half | col chunk of 256), k-part of 256.
// Two k-part partials combined by atomicAdd (2 addends -> bitwise exact).
__global__ __launch_bounds__(256) void k_xz(
    const float* __restrict__ x, const float* __restrict__ Wz1,
    const float* __restrict__ Wz2, float* __restrict__ xz1,
    float* __restrict__ xz2) {
    const int br0  = blockIdx.x * 8;
    const int half = blockIdx.y >> 4;
    const int cb   = (blockIdx.y & 15) * 256;
    const int k0   = blockIdx.z * 256;
    const int t    = threadIdx.x;
    __shared__ float xs[8 * 256];
#pragma unroll
    for (int i = 0; i < 8; ++i)
        xs[i * 256 + t] = x[(br0 + i) * 512 + k0 + t];
    __syncthreads();

    const float* __restrict__ W   = half ? Wz2 : Wz1;
    float* __restrict__       out = half ? xz2 : xz1;
    const float* __restrict__ Wc  = W + (size_t)k0 * 4096 + cb + t;

    float acc[8];
#pragma unroll
    for (int r = 0; r < 8; ++r) acc[r] = 0.f;

#pragma unroll 4
    for (int k4 = 0; k4 < 64; ++k4) {
        float4 xr[8];
#pragma unroll
        for (int r = 0; r < 8; ++r)
            xr[r] = *(const float4*)(xs + r * 256 + k4 * 4);
        const float* wp = Wc + (size_t)k4 * 4 * 4096;
        float w0 = wp[0], w1 = wp[4096], w2 = wp[8192], w3 = wp[12288];
#pragma unroll
        for (int r = 0; r < 8; ++r) {
            acc[r] = fmaf(xr[r].x, w0, acc[r]);
            acc[r] = fmaf(xr[r].y, w1, acc[r]);
            acc[r] = fmaf(xr[r].z, w2, acc[r]);
            acc[r] = fmaf(xr[r].w, w3, acc[r]);
        }
    }
#pragma unroll
    for (int r = 0; r < 8; ++r)
        atomicAdd(out + (br0 + r) * 4096 + cb + t, acc[r]);
}

// ---------------- Kernel 3: MFMA bilinear + rownorm + tanh + dot ------------
// 2048 blocks: blockIdx.x = r*2 + gh; block handles g in [gh*256, gh*256+256)
__global__ __launch_bounds__(256, 6) void k_main(
    const float* __restrict__ xz1, const float* __restrict__ xz2,
    const float* __restrict__ Wz1, const float* __restrict__ Wz2,
    const float* __restrict__ hbuf, float* __restrict__ yout,
    float* __restrict__ qout) {
    const int bx = blockIdx.x;
    const int r  = bx >> 1, gh = bx & 1;
    const int br = r >> 4, a = r & 15;
    const int t  = threadIdx.x;
    const int l  = t & 63, wv = t >> 6;
    const int hi = l >> 5, l31 = l & 31;

    __shared__ __align__(16) _Float16 z1t[513 * 8];   // [d][h], row 512 = zeros
    __shared__ __align__(16) _Float16 z2t[257 * 8];   // [g_local][h], row 256 = 0
    __shared__ float2 ABs[256];
    __shared__ float  vs[512];
    __shared__ float  ys[256];
    __shared__ float  red[45 * 4];
    __shared__ float  Ssum[45];
    __shared__ float  wq[4];

    const float* __restrict__ x1  = xz1 + br * 4096;
    const float* __restrict__ x2  = xz2 + br * 4096;
    const float* __restrict__ w1r = Wz1 + (512 + a) * 4096;
    const float* __restrict__ w2r = Wz2 + (512 + a) * 4096;

    // ---- phase 1: stage z1 (full, f16) + stats, z2 (this half), v ----
    float pm[8], pg[36];
#pragma unroll
    for (int i = 0; i < 8; ++i) pm[i] = 0.f;
#pragma unroll
    for (int i = 0; i < 36; ++i) pg[i] = 0.f;

#pragma unroll
    for (int pass = 0; pass < 2; ++pass) {
        const int d = t + pass * 256;
        float z1v[8];
#pragma unroll
        for (int h = 0; h < 8; ++h) z1v[h] = x1[h * 512 + d] + w1r[h * 512 + d];
        half8 h1;
#pragma unroll
        for (int h = 0; h < 8; ++h) h1[h] = (_Float16)z1v[h];
        *(half8*)(z1t + d * 8) = h1;
        float zr[8];
#pragma unroll
        for (int h = 0; h < 8; ++h) zr[h] = (float)h1[h];
#pragma unroll
        for (int h = 0; h < 8; ++h) pm[h] += zr[h];
        int id = 0;
#pragma unroll
        for (int h = 0; h < 8; ++h)
#pragma unroll
            for (int h2_ = h; h2_ < 8; ++h2_) { pg[id] += zr[h] * zr[h2_]; ++id; }
    }
    {
        const int g = gh * 256 + t;
        float z2v[8];
#pragma unroll
        for (int h = 0; h < 8; ++h) z2v[h] = x2[h * 512 + g] + w2r[h * 512 + g];
        half8 h2v;
#pragma unroll
        for (int h = 0; h < 8; ++h) h2v[h] = (_Float16)z2v[h];
        *(half8*)(z2t + t * 8) = h2v;
    }
    if (t == 0) {
        half8 hz = {};
        *(half8*)(z1t + 512 * 8) = hz;
        *(half8*)(z2t + 256 * 8) = hz;
    }
    float v0 = hbuf[br * 512 + t], v1 = hbuf[br * 512 + t + 256];
    vs[t] = v0; vs[t + 256] = v1;
    float pv = v0 + v1;

#pragma unroll
    for (int m = 1; m < 64; m <<= 1) {
#pragma unroll
        for (int i = 0; i < 8; ++i)  pm[i] += __shfl_xor(pm[i], m);
#pragma unroll
        for (int i = 0; i < 36; ++i) pg[i] += __shfl_xor(pg[i], m);
        pv += __shfl_xor(pv, m);
    }
    if (l == 0) {
#pragma unroll
        for (int i = 0; i < 8; ++i)  red[i * 4 + wv]       = pm[i];
#pragma unroll
        for (int i = 0; i < 36; ++i) red[(8 + i) * 4 + wv] = pg[i];
        red[44 * 4 + wv] = pv;
    }
    __syncthreads();
    if (t < 45) Ssum[t] = red[t * 4 + 0] + red[t * 4 + 1] + red[t * 4 + 2] + red[t * 4 + 3];
    __syncthreads();

    // ---- phase 2: per-g scale/bias (folded with 2*log2e), 256 local g ----
    const float C2LE = 2.8853900817779268f;  // 2*log2(e)
    {
        half8 hz = *(const half8*)(z2t + t * 8);
        float zv[8];
#pragma unroll
        for (int h = 0; h < 8; ++h) zv[h] = (float)hz[h];
        float mean = 0.f;
#pragma unroll
        for (int h = 0; h < 8; ++h) mean = fmaf(zv[h], Ssum[h], mean);
        mean *= (1.0f / 512.0f);
        float e2 = 0.f;
        int id = 0;
#pragma unroll
        for (int h = 0; h < 8; ++h)
#pragma unroll
            for (int h2_ = h; h2_ < 8; ++h2_) {
                float p = zv[h] * zv[h2_] * Ssum[8 + id];
                e2 += (h2_ == h) ? p : 2.0f * p;
                ++id;
            }
        e2 *= (1.0f / 512.0f);
        float var  = e2 - mean * mean;
        float sd   = sqrtf(fmaxf(var, 0.f));
        float rstd = 1.0f / (sd + EPS);
        ABs[t] = make_float2(rstd * C2LE, -mean * rstd * C2LE);
    }
    __syncthreads();

    const float Vsum = Ssum[44];

    // ---- phase 3: MFMA tiles + finish (3 VALU + 2 trans per element) ----
    const f32x16 CZ = {0.f, 0.f, 0.f, 0.f, 0.f, 0.f, 0.f, 0.f,
                       0.f, 0.f, 0.f, 0.f, 0.f, 0.f, 0.f, 0.f};
    float qacc = 0.f;
#pragma unroll 1
    for (int mi = 0; mi < 2; ++mi) {
        const int m0 = (wv * 2 + mi) * 32;              // local g tile base
        const int arow = hi ? 256 : (m0 + l31);
        const half8 Af = *(const half8*)(z2t + arow * 8);
        float2 abv[16];
#pragma unroll
        for (int rg = 0; rg < 16; ++rg)
            abv[rg] = ABs[m0 + (rg & 3) + 8 * (rg >> 2) + 4 * hi];
        float yac[16];
#pragma unroll
        for (int i = 0; i < 16; ++i) yac[i] = 0.f;

#pragma unroll 1
        for (int nt = 0; nt < 16; ++nt) {
            const int n0 = nt * 32;
            const int brow = hi ? 512 : (n0 + l31);
            const half8 Bf = *(const half8*)(z1t + brow * 8);
            const float vv = vs[n0 + l31];
            f32x16 D = __builtin_amdgcn_mfma_f32_32x32x16_f16(Af, Bf, CZ, 0, 0, 0);
#pragma unroll
            for (int i = 0; i < 16; ++i) {
                float wn = fmaf(D[i], abv[i].x, abv[i].y);   // 2x*log2e
                float e  = __builtin_amdgcn_exp2f(wn);       // e^{2x}
                float r1 = __builtin_amdgcn_rcpf(e + 1.0f);
                yac[i] = fmaf(vv, r1, yac[i]);               // sum v/(e^{2x}+1)
            }
        }
#pragma unroll
        for (int i = 0; i < 16; ++i) {
#pragma unroll
            for (int m = 1; m <= 16; m <<= 1) yac[i] += __shfl_xor(yac[i], m);
        }
        if (l31 == 0) {
#pragma unroll
            for (int i = 0; i < 16; ++i) {
                const int g = m0 + (i & 3) + 8 * (i >> 2) + 4 * hi;
                float yv = fmaf(-2.0f, yac[i], Vsum);        // Vsum - 2*sum
                ys[g] = yv;
                qacc = fmaf(yv, yv, qacc);
            }
        }
    }
    qacc += __shfl_xor(qacc, 32);
    if (l == 0) wq[wv] = qacc;
    __syncthreads();
    if (t == 0) atomicAdd(qout + r, (wq[0] + wq[1] + wq[2] + wq[3]) * (1.0f / 512.0f));
    yout[r * 512 + gh * 256 + t] = ys[t];
}

// ---------------------------------------------------------------------------
extern "C" void kernel_launch(void* const* d_in, const int* in_sizes, int n_in,
                              void* d_out, int out_size, void* d_ws, size_t ws_size,
                              hipStream_t stream) {
    const float* x   = (const float*)d_in[0];   // (64, 512)
    const float* Wh  = (const float*)d_in[1];   // (512, 512)
    const float* bh  = (const float*)d_in[2];   // (512,)
    const float* ls  = (const float*)d_in[3];   // (512,)
    const float* lb  = (const float*)d_in[4];   // (512,)
    const float* Wz1 = (const float*)d_in[5];   // (528, 4096)
    const float* Wz2 = (const float*)d_in[6];   // (528, 4096)

    float* out  = (float*)d_out;
    float* hout = out;                 // 64*512
    float* qout = out + 32768;         // 64*16
    float* yout = out + 33792;         // 1024*512

    float* xz1 = (float*)d_ws;         // 64*4096 floats
    float* xz2 = xz1 + 64 * 4096;      // 64*4096 floats

    hipMemsetAsync(d_ws, 0, (size_t)2 * 64 * 4096 * sizeof(float), stream);
    hipMemsetAsync(qout, 0, 64 * 16 * sizeof(float), stream);

    k_fch_ln<<<64, 512, 0, stream>>>(x, Wh, bh, ls, lb, hout);
    k_xz<<<dim3(8, 32, 2), 256, 0, stream>>>(x, Wz1, Wz2, xz1, xz2);
    k_main<<<2048, 256, 0, stream>>>(xz1, xz2, Wz1, Wz2, hout, yout, qout);
}